// Round 7
// baseline (822.574 us; speedup 1.0000x reference)
//
#include <hip/hip_runtime.h>
#include <hip/hip_bf16.h>

// ---------------- degree histogram ----------------
__global__ void deg_kernel(const int* __restrict__ dst, int* __restrict__ cnt, int E) {
    int e = blockIdx.x * 256 + threadIdx.x;
    if (e < E) atomicAdd(&cnt[dst[e]], 1);
}

// ---------------- single-block scan: rowptr/dinv/self-loop in ONE dispatch ----------------
// 1024 threads, each owns C = ceil(N/1024) contiguous rows: serial partial sums,
// Hillis-Steele LDS scan of 1024 partials, then serial emit.
__global__ __launch_bounds__(1024) void scan_all(const int* __restrict__ cnt,
                                                 int* __restrict__ rowptr,
                                                 float* __restrict__ dinv,
                                                 int* __restrict__ col, int N) {
    __shared__ int p[1024];
    int tid = threadIdx.x;
    int C = (N + 1023) / 1024;
    int base = tid * C;
    int sum = 0;
    for (int j = 0; j < C; ++j) {
        int i = base + j;
        if (i < N) sum += cnt[i] + 1;
    }
    p[tid] = sum;
    __syncthreads();
    for (int off = 1; off < 1024; off <<= 1) {
        int x = (tid >= off) ? p[tid - off] : 0;
        __syncthreads();
        p[tid] += x;
        __syncthreads();
    }
    int run = (tid == 0) ? 0 : p[tid - 1];
    for (int j = 0; j < C; ++j) {
        int i = base + j;
        if (i < N) {
            int c1 = cnt[i] + 1;
            run += c1;
            rowptr[i + 1] = run;
            dinv[i] = rsqrtf((float)c1);
            col[run - c1] = i;          // self-loop occupies slot 0 of row i
        }
    }
    if (tid == 0) rowptr[0] = 0;
}

// ---------------- edge fill + input prescale (independent work, one dispatch) ----------------
// Blocks [0, nbE): fill CSR real edges, reusing cnt[] (= deg) as cursor via atomicSub.
// Blocks [nbE, ...): Xs = dinv ⊙ X0 row-wise (layer-1's prescaled features).
__global__ __launch_bounds__(256) void edgefill_prescale(const int* __restrict__ src,
                                                         const int* __restrict__ dst,
                                                         const int* __restrict__ rowptr,
                                                         int* __restrict__ cnt,
                                                         int* __restrict__ col,
                                                         const float* __restrict__ X0,
                                                         const float* __restrict__ dinv,
                                                         float* __restrict__ Xs,
                                                         int E, int N, int nbE) {
    int b = blockIdx.x;
    if (b < nbE) {
        int e = b * 256 + threadIdx.x;
        if (e < E) {
            int d = dst[e];
            int pos = rowptr[d] + atomicSub(&cnt[d], 1);
            col[pos] = src[e];
        }
    } else {
        int i = (b - nbE) * 256 + threadIdx.x;   // over N*32 float4s
        if (i < N * 32) {
            float dsc = dinv[i >> 5];
            float4 v = ((const float4*)X0)[i];
            v.x *= dsc; v.y *= dsc; v.z *= dsc; v.w *= dsc;
            ((float4*)Xs)[i] = v;
        }
    }
}

// ---------------- fused GCN layer: Out = post( (Â_norm · Xs) @ W + b ) ----------------
// Aggregate-then-transform (A(XW) == (AX)W).  Per block: 128 output rows.
// Phase A: gather y = dinv_n · Σ x̃_s for the block's 128 rows straight into the
// GEMM's LDS X-tile (transposed [k][row]).  Phase B: 128x128 @ 128x128 LDS GEMM,
// W staged per k0-tile (512 coop float4 loads — amortized over 128 rows; this is
// what round-4's 8-row fusion lacked).  mode=1: out = relu(.)·dinv (next x̃);
// mode=0: plain (final embeddings).
__global__ __launch_bounds__(256) void fused_layer(const float* __restrict__ Xs,
                                                   const float* __restrict__ dinv,
                                                   const int* __restrict__ rowptr,
                                                   const int* __restrict__ col,
                                                   const float* __restrict__ W,
                                                   const float* __restrict__ bias,
                                                   float* __restrict__ Out,
                                                   int n, int mode) {
    __shared__ __align__(16) float xs[128][132];   // [k][row], +4 pad
    __shared__ __align__(16) float ws[16][128];    // [k][col] W tile
    int tid = threadIdx.x;
    int row0 = blockIdx.x * 128;

    // ---- phase A: gather 128 rows (16 groups of 8 rows x 32 lanes x float4) ----
    {
        int sub = tid >> 5;               // row-in-group 0..7
        int t = (tid & 31) * 4;           // dim offset
        for (int g = 0; g < 16; ++g) {
            int rr = g * 8 + sub;
            int node = row0 + rr;
            float ax = 0.f, ay = 0.f, az = 0.f, aw = 0.f;
            if (node < n) {
                int beg = rowptr[node], end = rowptr[node + 1];
                int k = beg;
                for (; k + 4 <= end; k += 4) {
                    int s0 = col[k], s1 = col[k + 1], s2 = col[k + 2], s3 = col[k + 3];
                    float4 h0 = *(const float4*)&Xs[(size_t)s0 * 128 + t];
                    float4 h1 = *(const float4*)&Xs[(size_t)s1 * 128 + t];
                    float4 h2 = *(const float4*)&Xs[(size_t)s2 * 128 + t];
                    float4 h3 = *(const float4*)&Xs[(size_t)s3 * 128 + t];
                    ax += (h0.x + h1.x) + (h2.x + h3.x);
                    ay += (h0.y + h1.y) + (h2.y + h3.y);
                    az += (h0.z + h1.z) + (h2.z + h3.z);
                    aw += (h0.w + h1.w) + (h2.w + h3.w);
                }
                for (; k < end; ++k) {
                    float4 h = *(const float4*)&Xs[(size_t)col[k] * 128 + t];
                    ax += h.x; ay += h.y; az += h.z; aw += h.w;
                }
                float dn = dinv[node];
                ax *= dn; ay *= dn; az *= dn; aw *= dn;
            }
            // transposed store into the GEMM X-tile
            xs[t + 0][rr] = ax; xs[t + 1][rr] = ay; xs[t + 2][rr] = az; xs[t + 3][rr] = aw;
        }
    }

    // ---- phase B: 128x128 GEMM, 8x8 outputs/thread ----
    int tx = tid & 15;    // cols {4tx..+3, 64+4tx..+3}
    int ty = tid >> 4;    // rows {4ty..+3, 64+4ty..+3}
    float acc[8][8] = {};
    for (int k0 = 0; k0 < 128; k0 += 16) {
        __syncthreads();   // first iter: xs writes done; later: ws reads done
        {
            const float4* Wv = (const float4*)&W[(size_t)k0 * 128];
            float4* wsv = (float4*)&ws[0][0];
            wsv[tid] = Wv[tid];
            wsv[tid + 256] = Wv[tid + 256];
        }
        __syncthreads();
#pragma unroll
        for (int kk = 0; kk < 16; ++kk) {
            float4 xa = *(float4*)&xs[k0 + kk][ty * 4];
            float4 xb = *(float4*)&xs[k0 + kk][ty * 4 + 64];
            float4 wa = *(float4*)&ws[kk][tx * 4];
            float4 wb = *(float4*)&ws[kk][tx * 4 + 64];
            float xr[8] = {xa.x, xa.y, xa.z, xa.w, xb.x, xb.y, xb.z, xb.w};
            float wr[8] = {wa.x, wa.y, wa.z, wa.w, wb.x, wb.y, wb.z, wb.w};
#pragma unroll
            for (int ii = 0; ii < 8; ++ii)
#pragma unroll
                for (int jj = 0; jj < 8; ++jj)
                    acc[ii][jj] += xr[ii] * wr[jj];
        }
    }

    // ---- epilogue: bias, then mode post-op ----
    float4 ba = *(const float4*)&bias[tx * 4];
    float4 bb = *(const float4*)&bias[64 + tx * 4];
#pragma unroll
    for (int ii = 0; ii < 8; ++ii) {
        int gr = row0 + ((ii < 4) ? (ty * 4 + ii) : (64 + ty * 4 + ii - 4));
        if (gr < n) {
            float4 v0 = make_float4(acc[ii][0] + ba.x, acc[ii][1] + ba.y,
                                    acc[ii][2] + ba.z, acc[ii][3] + ba.w);
            float4 v1 = make_float4(acc[ii][4] + bb.x, acc[ii][5] + bb.y,
                                    acc[ii][6] + bb.z, acc[ii][7] + bb.w);
            if (mode) {
                float dn = dinv[gr];
                v0.x = fmaxf(v0.x, 0.f) * dn; v0.y = fmaxf(v0.y, 0.f) * dn;
                v0.z = fmaxf(v0.z, 0.f) * dn; v0.w = fmaxf(v0.w, 0.f) * dn;
                v1.x = fmaxf(v1.x, 0.f) * dn; v1.y = fmaxf(v1.y, 0.f) * dn;
                v1.z = fmaxf(v1.z, 0.f) * dn; v1.w = fmaxf(v1.w, 0.f) * dn;
            }
            *(float4*)&Out[(size_t)gr * 128 + tx * 4] = v0;
            *(float4*)&Out[(size_t)gr * 128 + 64 + tx * 4] = v1;
        }
    }
}

// ---------------- edge decoder: out[e] = dot(X[u], X[v]) ----------------
// 16 lanes per edge, 8 floats per lane (2x float4) -> 4 gathers in flight/lane.
__global__ __launch_bounds__(256) void decoder(const float* __restrict__ X,
                                               const int* __restrict__ eli,
                                               float* __restrict__ out, int EL) {
    int e = blockIdx.x * 16 + (threadIdx.x >> 4);
    int lane = threadIdx.x & 15;
    if (e >= EL) return;
    int u = eli[e], v = eli[EL + e];
    const float4* Xu = (const float4*)&X[(size_t)u * 128 + lane * 8];
    const float4* Xv = (const float4*)&X[(size_t)v * 128 + lane * 8];
    float4 a0 = Xu[0], a1 = Xu[1];
    float4 b0 = Xv[0], b1 = Xv[1];
    float d = a0.x * b0.x + a0.y * b0.y + a0.z * b0.z + a0.w * b0.w
            + a1.x * b1.x + a1.y * b1.y + a1.z * b1.z + a1.w * b1.w;
#pragma unroll
    for (int off = 8; off > 0; off >>= 1) d += __shfl_xor(d, off);
    if (lane == 0) out[e] = d;
}

extern "C" void kernel_launch(void* const* d_in, const int* in_sizes, int n_in,
                              void* d_out, int out_size, void* d_ws, size_t ws_size,
                              hipStream_t stream) {
    const float* x0 = (const float*)d_in[0];
    const float* W1 = (const float*)d_in[1];
    const float* b1 = (const float*)d_in[2];
    const float* W2 = (const float*)d_in[3];
    const float* b2 = (const float*)d_in[4];
    const float* W3 = (const float*)d_in[5];
    const float* b3 = (const float*)d_in[6];
    const int* ei   = (const int*)d_in[7];
    const int* eli  = (const int*)d_in[8];
    float* out = (float*)d_out;

    const int D = 128;
    const int N  = in_sizes[0] / D;
    const int E  = in_sizes[7] / 2;
    const int EL = in_sizes[8] / 2;

    const int* src = ei;        // edge_index[0]
    const int* dst = ei + E;    // edge_index[1]

    // -------- workspace carve-up (256B aligned) --------
    char* ws = (char*)d_ws;
    size_t off = 0;
    auto alloc = [&](size_t bytes) -> void* {
        off = (off + 255) & ~(size_t)255;
        void* p = ws + off;
        off += bytes;
        return p;
    };
    int*   cnt    = (int*)alloc((size_t)N * sizeof(int));
    int*   rowptr = (int*)alloc((size_t)(N + 1) * sizeof(int));
    float* dinv   = (float*)alloc((size_t)N * sizeof(float));
    int*   col    = (int*)alloc((size_t)(E + N) * sizeof(int));
    float* xbuf   = (float*)alloc((size_t)N * D * sizeof(float));
    float* hbuf   = (float*)alloc((size_t)N * D * sizeof(float));
    (void)ws_size;

    // zero the degree counters
    hipMemsetAsync(cnt, 0, (size_t)N * sizeof(int), stream);

    int nbE = (E + 255) / 256;
    int nbP = (N * 32 + 255) / 256;

    // ---- CSR build: 3 dispatches ----
    deg_kernel<<<nbE, 256, 0, stream>>>(dst, cnt, E);
    scan_all<<<1, 1024, 0, stream>>>(cnt, rowptr, dinv, col, N);
    edgefill_prescale<<<nbE + nbP, 256, 0, stream>>>(src, dst, rowptr, cnt, col,
                                                     x0, dinv, xbuf, E, N, nbE);

    int fusedGrid = (N + 127) / 128;

    // ---- 3 fused layers (gather into GEMM X-tile), ping-pong ----
    fused_layer<<<fusedGrid, 256, 0, stream>>>(xbuf, dinv, rowptr, col, W1, b1, hbuf, N, 1);
    fused_layer<<<fusedGrid, 256, 0, stream>>>(hbuf, dinv, rowptr, col, W2, b2, xbuf, N, 1);
    fused_layer<<<fusedGrid, 256, 0, stream>>>(xbuf, dinv, rowptr, col, W3, b3, hbuf, N, 0);

    // ---- decoder ----
    decoder<<<(EL + 15) / 16, 256, 0, stream>>>(hbuf, eli, out, EL);
}

// Round 8
// 663.999 us; speedup vs baseline: 1.2388x; 1.2388x over previous
//
#include <hip/hip_runtime.h>
#include <hip/hip_bf16.h>

// ---------------- degree histogram ----------------
__global__ void deg_kernel(const int* __restrict__ dst, int* __restrict__ cnt, int E) {
    int e = blockIdx.x * 256 + threadIdx.x;
    if (e < E) atomicAdd(&cnt[dst[e]], 1);
}

// ---------------- single-block scan: rowptr/dinv/self-loop in ONE dispatch ----------------
__global__ __launch_bounds__(1024) void scan_all(const int* __restrict__ cnt,
                                                 int* __restrict__ rowptr,
                                                 float* __restrict__ dinv,
                                                 int* __restrict__ col, int N) {
    __shared__ int p[1024];
    int tid = threadIdx.x;
    int C = (N + 1023) / 1024;
    int base = tid * C;
    int sum = 0;
    for (int j = 0; j < C; ++j) {
        int i = base + j;
        if (i < N) sum += cnt[i] + 1;
    }
    p[tid] = sum;
    __syncthreads();
    for (int off = 1; off < 1024; off <<= 1) {
        int x = (tid >= off) ? p[tid - off] : 0;
        __syncthreads();
        p[tid] += x;
        __syncthreads();
    }
    int run = (tid == 0) ? 0 : p[tid - 1];
    for (int j = 0; j < C; ++j) {
        int i = base + j;
        if (i < N) {
            int c1 = cnt[i] + 1;
            run += c1;
            rowptr[i + 1] = run;
            dinv[i] = rsqrtf((float)c1);
            col[run - c1] = i;          // self-loop occupies slot 0 of row i
        }
    }
    if (tid == 0) rowptr[0] = 0;
}

// ---------------- fill CSR with real edges (cnt reused as cursor via atomicSub) ----------------
__global__ void edgefill(const int* __restrict__ src, const int* __restrict__ dst,
                         const int* __restrict__ rowptr, int* __restrict__ cnt,
                         int* __restrict__ col, int E) {
    int e = blockIdx.x * 256 + threadIdx.x;
    if (e < E) {
        int d = dst[e];
        int pos = rowptr[d] + atomicSub(&cnt[d], 1);
        col[pos] = src[e];
    }
}

// ---------------- fp32 GEMM: H[N,128] = (X[N,128] @ W[128,128]) * dscale[row] ----------------
// (round-5 measured-best: 256 threads, 128x128 tile, 8x8 outputs/thread)
__global__ __launch_bounds__(256) void gemm128(const float* __restrict__ X,
                                               const float* __restrict__ W,
                                               const float* __restrict__ dscale,
                                               float* __restrict__ H, int Nrows) {
    __shared__ __align__(16) float xs[16][132];  // [k][row], +4 pad
    __shared__ __align__(16) float ws[16][128];  // [k][col]
    int tid = threadIdx.x;
    int tx = tid & 15;
    int ty = tid >> 4;
    int row0 = blockIdx.x * 128;
    float acc[8][8] = {};
    for (int k0 = 0; k0 < 128; k0 += 16) {
        {   // stage X tile transposed: xs[kk][r], 128 rows x 16 k
            int r = tid >> 2;
            int j = (tid & 3) * 4;
            int gr = row0 + r;
            float4 v = (gr < Nrows) ? *(const float4*)&X[(size_t)gr * 128 + k0 + j]
                                    : make_float4(0.f, 0.f, 0.f, 0.f);
            xs[j + 0][r] = v.x; xs[j + 1][r] = v.y; xs[j + 2][r] = v.z; xs[j + 3][r] = v.w;
            int gr2 = gr + 64;
            float4 u = (gr2 < Nrows) ? *(const float4*)&X[(size_t)gr2 * 128 + k0 + j]
                                     : make_float4(0.f, 0.f, 0.f, 0.f);
            xs[j + 0][r + 64] = u.x; xs[j + 1][r + 64] = u.y;
            xs[j + 2][r + 64] = u.z; xs[j + 3][r + 64] = u.w;
        }
        {   // stage W tile: 16 k x 128 c = 512 float4
            const float4* Wv = (const float4*)&W[(size_t)k0 * 128];
            float4* wsv = (float4*)&ws[0][0];
            wsv[tid] = Wv[tid];
            wsv[tid + 256] = Wv[tid + 256];
        }
        __syncthreads();
#pragma unroll
        for (int kk = 0; kk < 16; ++kk) {
            float4 xa = *(float4*)&xs[kk][ty * 4];
            float4 xb = *(float4*)&xs[kk][ty * 4 + 64];
            float4 wa = *(float4*)&ws[kk][tx * 4];
            float4 wb = *(float4*)&ws[kk][tx * 4 + 64];
            float xr[8] = {xa.x, xa.y, xa.z, xa.w, xb.x, xb.y, xb.z, xb.w};
            float wr[8] = {wa.x, wa.y, wa.z, wa.w, wb.x, wb.y, wb.z, wb.w};
#pragma unroll
            for (int i = 0; i < 8; ++i)
#pragma unroll
                for (int j = 0; j < 8; ++j)
                    acc[i][j] += xr[i] * wr[j];
        }
        __syncthreads();
    }
#pragma unroll
    for (int i = 0; i < 8; ++i) {
        int gr = row0 + ((i < 4) ? (ty * 4 + i) : (64 + ty * 4 + i - 4));
        if (gr < Nrows) {
            float s = dscale[gr];
            *(float4*)&H[(size_t)gr * 128 + tx * 4] =
                make_float4(acc[i][0] * s, acc[i][1] * s, acc[i][2] * s, acc[i][3] * s);
            *(float4*)&H[(size_t)gr * 128 + 64 + tx * 4] =
                make_float4(acc[i][4] * s, acc[i][5] * s, acc[i][6] * s, acc[i][7] * s);
        }
    }
}

// ---------------- XCD-slice CSR aggregation ----------------
// Block b: dim-slice (b&7) -> XCD (b&7) via round-robin dispatch, node chunk (b>>3).
// XCD s then only ever gathers slice s of H: 50K x 64B = 3.2MB, resident in its 4MB L2.
// 256 threads = 64 nodes x 4 lanes (float4/lane = 16 dims = one cache line per node-visit).
// out[n] = relu?(dinv[n]*sum(H'[s]) + b); H' pre-scaled by dinv[row] in gemm epilogue.
__global__ __launch_bounds__(256) void agg_sliced(const float* __restrict__ H,
                                                  const float* __restrict__ dinv,
                                                  const int* __restrict__ rowptr,
                                                  const int* __restrict__ col,
                                                  const float* __restrict__ bias,
                                                  float* __restrict__ out,
                                                  int n, int relu) {
    int slice = blockIdx.x & 7;
    int node = (blockIdx.x >> 3) * 64 + (threadIdx.x >> 2);
    if (node >= n) return;
    int t = slice * 16 + (threadIdx.x & 3) * 4;
    int beg = rowptr[node], end = rowptr[node + 1];
    float ax = 0.f, ay = 0.f, az = 0.f, aw = 0.f;
    int k = beg;
    for (; k + 4 <= end; k += 4) {
        int s0 = col[k], s1 = col[k + 1], s2 = col[k + 2], s3 = col[k + 3];
        float4 h0 = *(const float4*)&H[(size_t)s0 * 128 + t];
        float4 h1 = *(const float4*)&H[(size_t)s1 * 128 + t];
        float4 h2 = *(const float4*)&H[(size_t)s2 * 128 + t];
        float4 h3 = *(const float4*)&H[(size_t)s3 * 128 + t];
        ax += (h0.x + h1.x) + (h2.x + h3.x);
        ay += (h0.y + h1.y) + (h2.y + h3.y);
        az += (h0.z + h1.z) + (h2.z + h3.z);
        aw += (h0.w + h1.w) + (h2.w + h3.w);
    }
    for (; k < end; ++k) {
        float4 h = *(const float4*)&H[(size_t)col[k] * 128 + t];
        ax += h.x; ay += h.y; az += h.z; aw += h.w;
    }
    float dn = dinv[node];
    float4 bv = *(const float4*)&bias[t];
    float4 r = make_float4(ax * dn + bv.x, ay * dn + bv.y,
                           az * dn + bv.z, aw * dn + bv.w);
    if (relu) {
        r.x = fmaxf(r.x, 0.f); r.y = fmaxf(r.y, 0.f);
        r.z = fmaxf(r.z, 0.f); r.w = fmaxf(r.w, 0.f);
    }
    *(float4*)&out[(size_t)node * 128 + t] = r;
}

// ---------------- XCD-slice edge decoder ----------------
// Same slice->XCD affinity: block b computes the 16-dim partial dot for slice (b&7)
// and atomically accumulates into out[e] (pre-zeroed by hipMemsetAsync).
__global__ __launch_bounds__(256) void decoder_sliced(const float* __restrict__ X,
                                                      const int* __restrict__ eli,
                                                      float* __restrict__ out, int EL) {
    int slice = blockIdx.x & 7;
    int e = (blockIdx.x >> 3) * 64 + (threadIdx.x >> 2);
    if (e >= EL) return;
    int off = slice * 16 + (threadIdx.x & 3) * 4;
    int u = eli[e], v = eli[EL + e];
    float4 a = *(const float4*)&X[(size_t)u * 128 + off];
    float4 b = *(const float4*)&X[(size_t)v * 128 + off];
    float d = a.x * b.x + a.y * b.y + a.z * b.z + a.w * b.w;
    d += __shfl_xor(d, 1);
    d += __shfl_xor(d, 2);
    if ((threadIdx.x & 3) == 0) atomicAdd(&out[e], d);
}

extern "C" void kernel_launch(void* const* d_in, const int* in_sizes, int n_in,
                              void* d_out, int out_size, void* d_ws, size_t ws_size,
                              hipStream_t stream) {
    const float* x0 = (const float*)d_in[0];
    const float* W1 = (const float*)d_in[1];
    const float* b1 = (const float*)d_in[2];
    const float* W2 = (const float*)d_in[3];
    const float* b2 = (const float*)d_in[4];
    const float* W3 = (const float*)d_in[5];
    const float* b3 = (const float*)d_in[6];
    const int* ei   = (const int*)d_in[7];
    const int* eli  = (const int*)d_in[8];
    float* out = (float*)d_out;

    const int D = 128;
    const int N  = in_sizes[0] / D;
    const int E  = in_sizes[7] / 2;
    const int EL = in_sizes[8] / 2;

    const int* src = ei;        // edge_index[0]
    const int* dst = ei + E;    // edge_index[1]

    // -------- workspace carve-up (256B aligned) --------
    char* ws = (char*)d_ws;
    size_t off = 0;
    auto alloc = [&](size_t bytes) -> void* {
        off = (off + 255) & ~(size_t)255;
        void* p = ws + off;
        off += bytes;
        return p;
    };
    int*   cnt    = (int*)alloc((size_t)N * sizeof(int));
    int*   rowptr = (int*)alloc((size_t)(N + 1) * sizeof(int));
    float* dinv   = (float*)alloc((size_t)N * sizeof(float));
    int*   col    = (int*)alloc((size_t)(E + N) * sizeof(int));
    float* hbuf   = (float*)alloc((size_t)N * D * sizeof(float));
    float* xbuf   = (float*)alloc((size_t)N * D * sizeof(float));
    (void)ws_size;

    // zero degree counters + decoder accumulator
    hipMemsetAsync(cnt, 0, (size_t)N * sizeof(int), stream);
    hipMemsetAsync(out, 0, (size_t)EL * sizeof(float), stream);

    int nbE = (E + 255) / 256;

    // ---- build degree / dinv / CSR: 3 dispatches ----
    deg_kernel<<<nbE, 256, 0, stream>>>(dst, cnt, E);
    scan_all<<<1, 1024, 0, stream>>>(cnt, rowptr, dinv, col, N);
    edgefill<<<nbE, 256, 0, stream>>>(src, dst, rowptr, cnt, col, E);

    int gemmGrid = (N + 127) / 128;
    int aggGrid  = 8 * ((N + 63) / 64);
    int decGrid  = 8 * ((EL + 63) / 64);

    // ---- layer 1 ----
    gemm128<<<gemmGrid, 256, 0, stream>>>(x0, W1, dinv, hbuf, N);
    agg_sliced<<<aggGrid, 256, 0, stream>>>(hbuf, dinv, rowptr, col, b1, xbuf, N, 1);
    // ---- layer 2 ----
    gemm128<<<gemmGrid, 256, 0, stream>>>(xbuf, W2, dinv, hbuf, N);
    agg_sliced<<<aggGrid, 256, 0, stream>>>(hbuf, dinv, rowptr, col, b2, xbuf, N, 1);
    // ---- layer 3 ----
    gemm128<<<gemmGrid, 256, 0, stream>>>(xbuf, W3, dinv, hbuf, N);
    agg_sliced<<<aggGrid, 256, 0, stream>>>(hbuf, dinv, rowptr, col, b3, xbuf, N, 0);

    // ---- decoder (slice partial dots + atomic accumulate) ----
    decoder_sliced<<<decGrid, 256, 0, stream>>>(xbuf, eli, out, EL);
}

// Round 9
// 364.425 us; speedup vs baseline: 2.2572x; 1.8220x over previous
//
#include <hip/hip_runtime.h>
#include <hip/hip_bf16.h>
#include <hip/hip_fp16.h>

// ---------------- degree histogram ----------------
__global__ void deg_kernel(const int* __restrict__ dst, int* __restrict__ cnt, int E) {
    int e = blockIdx.x * 256 + threadIdx.x;
    if (e < E) atomicAdd(&cnt[dst[e]], 1);
}

// ---------------- hierarchical exclusive scan of (cnt[i]+1) -> rowptr ----------------
__global__ void scan1(const int* __restrict__ cnt, int* __restrict__ tmp,
                      int* __restrict__ bsum, int n) {
    __shared__ int s[256];
    int i = blockIdx.x * 256 + threadIdx.x;
    int v = (i < n) ? (cnt[i] + 1) : 0;
    s[threadIdx.x] = v;
    __syncthreads();
    for (int off = 1; off < 256; off <<= 1) {
        int x = (threadIdx.x >= off) ? s[threadIdx.x - off] : 0;
        __syncthreads();
        s[threadIdx.x] += x;
        __syncthreads();
    }
    if (i < n) tmp[i] = s[threadIdx.x];
    if (threadIdx.x == 255) bsum[blockIdx.x] = s[255];
}

__global__ void scan2(int* bsum, int nb) {
    __shared__ int s[256];
    int t = threadIdx.x;
    int v = (t < nb) ? bsum[t] : 0;
    s[t] = v;
    __syncthreads();
    for (int off = 1; off < 256; off <<= 1) {
        int x = (t >= off) ? s[t - off] : 0;
        __syncthreads();
        s[t] += x;
        __syncthreads();
    }
    if (t < nb) bsum[t] = s[t] - v;  // exclusive
}

// scan3 fused with dinv + self-loop CSR entry
__global__ void scan3(const int* __restrict__ tmp, const int* __restrict__ bsum,
                      const int* __restrict__ cnt, int* __restrict__ rowptr,
                      float* __restrict__ dinv, int* __restrict__ col, int n) {
    int i = blockIdx.x * 256 + threadIdx.x;
    if (i < n) {
        int inc = tmp[i] + bsum[blockIdx.x];   // inclusive scan of (cnt+1)
        rowptr[i + 1] = inc;
        int c1 = cnt[i] + 1;
        int r0 = inc - c1;                     // exclusive = rowptr[i]
        dinv[i] = rsqrtf((float)c1);
        col[r0] = i;                           // self-loop occupies slot 0 of row i
        if (i == 0) rowptr[0] = 0;
    }
}

// ---------------- fill CSR with real edges (cnt reused as cursor via atomicSub) ----------------
__global__ void edgefill(const int* __restrict__ src, const int* __restrict__ dst,
                         const int* __restrict__ rowptr, int* __restrict__ cnt,
                         int* __restrict__ col, int E) {
    int e = blockIdx.x * 256 + threadIdx.x;
    if (e < E) {
        int d = dst[e];
        int pos = rowptr[d] + atomicSub(&cnt[d], 1);
        col[pos] = src[e];
    }
}

// ---------------- fp32 GEMM -> fp16 out: H[N,128] = half((X @ W) * dscale[row]) ----------------
// round-5 measured-best structure: 256 threads, 128x128 tile, 8x8 outputs/thread.
// fp32 inputs/accumulation; only the H store is fp16 (halves agg's gather bytes).
__global__ __launch_bounds__(256) void gemm128h(const float* __restrict__ X,
                                                const float* __restrict__ W,
                                                const float* __restrict__ dscale,
                                                __half* __restrict__ H, int Nrows) {
    __shared__ __align__(16) float xs[16][132];  // [k][row], +4 pad
    __shared__ __align__(16) float ws[16][128];  // [k][col]
    int tid = threadIdx.x;
    int tx = tid & 15;
    int ty = tid >> 4;
    int row0 = blockIdx.x * 128;
    float acc[8][8] = {};
    for (int k0 = 0; k0 < 128; k0 += 16) {
        {   // stage X tile transposed: xs[kk][r], 128 rows x 16 k
            int r = tid >> 2;
            int j = (tid & 3) * 4;
            int gr = row0 + r;
            float4 v = (gr < Nrows) ? *(const float4*)&X[(size_t)gr * 128 + k0 + j]
                                    : make_float4(0.f, 0.f, 0.f, 0.f);
            xs[j + 0][r] = v.x; xs[j + 1][r] = v.y; xs[j + 2][r] = v.z; xs[j + 3][r] = v.w;
            int gr2 = gr + 64;
            float4 u = (gr2 < Nrows) ? *(const float4*)&X[(size_t)gr2 * 128 + k0 + j]
                                     : make_float4(0.f, 0.f, 0.f, 0.f);
            xs[j + 0][r + 64] = u.x; xs[j + 1][r + 64] = u.y;
            xs[j + 2][r + 64] = u.z; xs[j + 3][r + 64] = u.w;
        }
        {   // stage W tile: 16 k x 128 c = 512 float4
            const float4* Wv = (const float4*)&W[(size_t)k0 * 128];
            float4* wsv = (float4*)&ws[0][0];
            wsv[tid] = Wv[tid];
            wsv[tid + 256] = Wv[tid + 256];
        }
        __syncthreads();
#pragma unroll
        for (int kk = 0; kk < 16; ++kk) {
            float4 xa = *(float4*)&xs[kk][ty * 4];
            float4 xb = *(float4*)&xs[kk][ty * 4 + 64];
            float4 wa = *(float4*)&ws[kk][tx * 4];
            float4 wb = *(float4*)&ws[kk][tx * 4 + 64];
            float xr[8] = {xa.x, xa.y, xa.z, xa.w, xb.x, xb.y, xb.z, xb.w};
            float wr[8] = {wa.x, wa.y, wa.z, wa.w, wb.x, wb.y, wb.z, wb.w};
#pragma unroll
            for (int i = 0; i < 8; ++i)
#pragma unroll
                for (int j = 0; j < 8; ++j)
                    acc[i][j] += xr[i] * wr[j];
        }
        __syncthreads();
    }
#pragma unroll
    for (int i = 0; i < 8; ++i) {
        int gr = row0 + ((i < 4) ? (ty * 4 + i) : (64 + ty * 4 + i - 4));
        if (gr < Nrows) {
            float s = dscale[gr];
            ushort4 p0, p1;
            p0.x = __half_as_ushort(__float2half_rn(acc[i][0] * s));
            p0.y = __half_as_ushort(__float2half_rn(acc[i][1] * s));
            p0.z = __half_as_ushort(__float2half_rn(acc[i][2] * s));
            p0.w = __half_as_ushort(__float2half_rn(acc[i][3] * s));
            p1.x = __half_as_ushort(__float2half_rn(acc[i][4] * s));
            p1.y = __half_as_ushort(__float2half_rn(acc[i][5] * s));
            p1.z = __half_as_ushort(__float2half_rn(acc[i][6] * s));
            p1.w = __half_as_ushort(__float2half_rn(acc[i][7] * s));
            *(ushort4*)&H[(size_t)gr * 128 + tx * 4] = p0;
            *(ushort4*)&H[(size_t)gr * 128 + 64 + tx * 4] = p1;
        }
    }
}

// ---------------- CSR aggregation over fp16 H: out = relu?(dinv[n]*sum(H'[s]) + b) ----------------
// H' pre-scaled by dinv[row] (fp16).  Row = 256B.  256 threads = 16 nodes x 16 lanes;
// each lane owns 8 dims (one uint4 = 8 halfs = 16B per gather).  Unroll-4 -> 4
// independent dwordx4 gathers in flight.  fp32 accumulation.
__global__ __launch_bounds__(256) void agg_h(const __half* __restrict__ H,
                                             const float* __restrict__ dinv,
                                             const int* __restrict__ rowptr,
                                             const int* __restrict__ col,
                                             const float* __restrict__ bias,
                                             float* __restrict__ out,
                                             int n, int relu) {
    int node = blockIdx.x * 16 + (threadIdx.x >> 4);
    int t = (threadIdx.x & 15) * 8;       // dim offset (halfs)
    if (node >= n) return;
    int beg = rowptr[node], end = rowptr[node + 1];
    float a[8] = {};
    int k = beg;
    for (; k + 4 <= end; k += 4) {
        int s0 = col[k], s1 = col[k + 1], s2 = col[k + 2], s3 = col[k + 3];
        uint4 r0 = *(const uint4*)&H[(size_t)s0 * 128 + t];
        uint4 r1 = *(const uint4*)&H[(size_t)s1 * 128 + t];
        uint4 r2 = *(const uint4*)&H[(size_t)s2 * 128 + t];
        uint4 r3 = *(const uint4*)&H[(size_t)s3 * 128 + t];
        const __half2* h0 = (const __half2*)&r0;
        const __half2* h1 = (const __half2*)&r1;
        const __half2* h2 = (const __half2*)&r2;
        const __half2* h3 = (const __half2*)&r3;
#pragma unroll
        for (int j = 0; j < 4; ++j) {
            float2 f0 = __half22float2(h0[j]);
            float2 f1 = __half22float2(h1[j]);
            float2 f2 = __half22float2(h2[j]);
            float2 f3 = __half22float2(h3[j]);
            a[2 * j]     += (f0.x + f1.x) + (f2.x + f3.x);
            a[2 * j + 1] += (f0.y + f1.y) + (f2.y + f3.y);
        }
    }
    for (; k < end; ++k) {
        uint4 r0 = *(const uint4*)&H[(size_t)col[k] * 128 + t];
        const __half2* h0 = (const __half2*)&r0;
#pragma unroll
        for (int j = 0; j < 4; ++j) {
            float2 f0 = __half22float2(h0[j]);
            a[2 * j] += f0.x;
            a[2 * j + 1] += f0.y;
        }
    }
    float dn = dinv[node];
    float4 b0 = *(const float4*)&bias[t];
    float4 b1 = *(const float4*)&bias[t + 4];
    float4 v0 = make_float4(a[0] * dn + b0.x, a[1] * dn + b0.y,
                            a[2] * dn + b0.z, a[3] * dn + b0.w);
    float4 v1 = make_float4(a[4] * dn + b1.x, a[5] * dn + b1.y,
                            a[6] * dn + b1.z, a[7] * dn + b1.w);
    if (relu) {
        v0.x = fmaxf(v0.x, 0.f); v0.y = fmaxf(v0.y, 0.f);
        v0.z = fmaxf(v0.z, 0.f); v0.w = fmaxf(v0.w, 0.f);
        v1.x = fmaxf(v1.x, 0.f); v1.y = fmaxf(v1.y, 0.f);
        v1.z = fmaxf(v1.z, 0.f); v1.w = fmaxf(v1.w, 0.f);
    }
    *(float4*)&out[(size_t)node * 128 + t] = v0;
    *(float4*)&out[(size_t)node * 128 + t + 4] = v1;
}

// ---------------- edge decoder: out[e] = dot(X[u], X[v]) ----------------
// 16 lanes per edge, 8 floats per lane (2x float4) -> 4 gathers in flight/lane.
__global__ __launch_bounds__(256) void decoder(const float* __restrict__ X,
                                               const int* __restrict__ eli,
                                               float* __restrict__ out, int EL) {
    int e = blockIdx.x * 16 + (threadIdx.x >> 4);
    int lane = threadIdx.x & 15;
    if (e >= EL) return;
    int u = eli[e], v = eli[EL + e];
    const float4* Xu = (const float4*)&X[(size_t)u * 128 + lane * 8];
    const float4* Xv = (const float4*)&X[(size_t)v * 128 + lane * 8];
    float4 a0 = Xu[0], a1 = Xu[1];
    float4 b0 = Xv[0], b1 = Xv[1];
    float d = a0.x * b0.x + a0.y * b0.y + a0.z * b0.z + a0.w * b0.w
            + a1.x * b1.x + a1.y * b1.y + a1.z * b1.z + a1.w * b1.w;
#pragma unroll
    for (int off = 8; off > 0; off >>= 1) d += __shfl_xor(d, off);
    if (lane == 0) out[e] = d;
}

extern "C" void kernel_launch(void* const* d_in, const int* in_sizes, int n_in,
                              void* d_out, int out_size, void* d_ws, size_t ws_size,
                              hipStream_t stream) {
    const float* x0 = (const float*)d_in[0];
    const float* W1 = (const float*)d_in[1];
    const float* b1 = (const float*)d_in[2];
    const float* W2 = (const float*)d_in[3];
    const float* b2 = (const float*)d_in[4];
    const float* W3 = (const float*)d_in[5];
    const float* b3 = (const float*)d_in[6];
    const int* ei   = (const int*)d_in[7];
    const int* eli  = (const int*)d_in[8];
    float* out = (float*)d_out;

    const int D = 128;
    const int N  = in_sizes[0] / D;
    const int E  = in_sizes[7] / 2;
    const int EL = in_sizes[8] / 2;

    const int* src = ei;        // edge_index[0]
    const int* dst = ei + E;    // edge_index[1]

    // -------- workspace carve-up (256B aligned) --------
    char* ws = (char*)d_ws;
    size_t off = 0;
    auto alloc = [&](size_t bytes) -> void* {
        off = (off + 255) & ~(size_t)255;
        void* p = ws + off;
        off += bytes;
        return p;
    };
    int*    cnt    = (int*)alloc((size_t)N * sizeof(int));
    int*    tmp    = (int*)alloc((size_t)N * sizeof(int));
    int*    bsum   = (int*)alloc(256 * sizeof(int));
    int*    rowptr = (int*)alloc((size_t)(N + 1) * sizeof(int));
    float*  dinv   = (float*)alloc((size_t)N * sizeof(float));
    int*    col    = (int*)alloc((size_t)(E + N) * sizeof(int));
    __half* hbuf   = (__half*)alloc((size_t)N * D * sizeof(__half));
    float*  xbuf   = (float*)alloc((size_t)N * D * sizeof(float));
    (void)ws_size;

    // zero the degree counters
    hipMemsetAsync(cnt, 0, (size_t)N * sizeof(int), stream);

    int nbN = (N + 255) / 256;
    int nbE = (E + 255) / 256;

    // ---- build degree / dinv / CSR ----
    deg_kernel<<<nbE, 256, 0, stream>>>(dst, cnt, E);
    scan1<<<nbN, 256, 0, stream>>>(cnt, tmp, bsum, N);
    scan2<<<1, 256, 0, stream>>>(bsum, nbN);
    scan3<<<nbN, 256, 0, stream>>>(tmp, bsum, cnt, rowptr, dinv, col, N);
    edgefill<<<nbE, 256, 0, stream>>>(src, dst, rowptr, cnt, col, E);

    int gemmGrid = (N + 127) / 128;
    int aggGrid  = (N + 15) / 16;

    // ---- layer 1 ----
    gemm128h<<<gemmGrid, 256, 0, stream>>>(x0, W1, dinv, hbuf, N);
    agg_h<<<aggGrid, 256, 0, stream>>>(hbuf, dinv, rowptr, col, b1, xbuf, N, 1);
    // ---- layer 2 ----
    gemm128h<<<gemmGrid, 256, 0, stream>>>(xbuf, W2, dinv, hbuf, N);
    agg_h<<<aggGrid, 256, 0, stream>>>(hbuf, dinv, rowptr, col, b2, xbuf, N, 1);
    // ---- layer 3 ----
    gemm128h<<<gemmGrid, 256, 0, stream>>>(xbuf, W3, dinv, hbuf, N);
    agg_h<<<aggGrid, 256, 0, stream>>>(hbuf, dinv, rowptr, col, b3, xbuf, N, 0);

    // ---- decoder ----
    decoder<<<(EL + 15) / 16, 256, 0, stream>>>(xbuf, eli, out, EL);
}

// Round 10
// 362.634 us; speedup vs baseline: 2.2683x; 1.0049x over previous
//
#include <hip/hip_runtime.h>
#include <hip/hip_bf16.h>
#include <hip/hip_fp16.h>

// ---------------- hierarchical exclusive scan of (cnt[i]+1) -> rowptr ----------------
__global__ void scan1(const int* __restrict__ cnt, int* __restrict__ tmp,
                      int* __restrict__ bsum, int n) {
    __shared__ int s[256];
    int i = blockIdx.x * 256 + threadIdx.x;
    int v = (i < n) ? (cnt[i] + 1) : 0;
    s[threadIdx.x] = v;
    __syncthreads();
    for (int off = 1; off < 256; off <<= 1) {
        int x = (threadIdx.x >= off) ? s[threadIdx.x - off] : 0;
        __syncthreads();
        s[threadIdx.x] += x;
        __syncthreads();
    }
    if (i < n) tmp[i] = s[threadIdx.x];
    if (threadIdx.x == 255) bsum[blockIdx.x] = s[255];
}

__global__ void scan2(int* bsum, int nb) {
    __shared__ int s[256];
    int t = threadIdx.x;
    int v = (t < nb) ? bsum[t] : 0;
    s[t] = v;
    __syncthreads();
    for (int off = 1; off < 256; off <<= 1) {
        int x = (t >= off) ? s[t - off] : 0;
        __syncthreads();
        s[t] += x;
        __syncthreads();
    }
    if (t < nb) bsum[t] = s[t] - v;  // exclusive
}

// scan3 fused with dinv + self-loop CSR entry
__global__ void scan3(const int* __restrict__ tmp, const int* __restrict__ bsum,
                      const int* __restrict__ cnt, int* __restrict__ rowptr,
                      float* __restrict__ dinv, int* __restrict__ col, int n) {
    int i = blockIdx.x * 256 + threadIdx.x;
    if (i < n) {
        int inc = tmp[i] + bsum[blockIdx.x];   // inclusive scan of (cnt+1)
        rowptr[i + 1] = inc;
        int c1 = cnt[i] + 1;
        int r0 = inc - c1;                     // exclusive = rowptr[i]
        dinv[i] = rsqrtf((float)c1);
        col[r0] = i;                           // self-loop occupies slot 0 of row i
        if (i == 0) rowptr[0] = 0;
    }
}

// ---------------- edge fill, 4 edges/thread (4 independent atomic chains in flight) ----------------
// cnt[] (still = deg) reused as cursor via atomicSub; slots rowptr[d]+1..rowptr[d]+deg.
__global__ __launch_bounds__(256) void edgefill4(const int* __restrict__ src,
                                                 const int* __restrict__ dst,
                                                 const int* __restrict__ rowptr,
                                                 int* __restrict__ cnt,
                                                 int* __restrict__ col, int E) {
    int base = blockIdx.x * 1024 + threadIdx.x * 4;
    if (base + 3 < E) {
        int d0 = dst[base], d1 = dst[base + 1], d2 = dst[base + 2], d3 = dst[base + 3];
        int s0 = src[base], s1 = src[base + 1], s2 = src[base + 2], s3 = src[base + 3];
        int p0 = rowptr[d0] + atomicSub(&cnt[d0], 1);
        int p1 = rowptr[d1] + atomicSub(&cnt[d1], 1);
        int p2 = rowptr[d2] + atomicSub(&cnt[d2], 1);
        int p3 = rowptr[d3] + atomicSub(&cnt[d3], 1);
        col[p0] = s0; col[p1] = s1; col[p2] = s2; col[p3] = s3;
    } else {
        for (int e = base; e < E; ++e) {
            int d = dst[e];
            col[rowptr[d] + atomicSub(&cnt[d], 1)] = src[e];
        }
    }
}

// ---------------- MEGA: degree histogram (4 edges/thread) + layer-1 GEMM (unscaled) ----------------
// Blocks [0, degBlocks): cnt[dst[e]]++.  Blocks [degBlocks, ...): H1 = half(x0 @ W1)
// (no dinv scale — dinv isn't ready yet; agg layer 1 gathers dinv[s] per edge instead).
__global__ __launch_bounds__(256) void deg_gemm1(const int* __restrict__ dst,
                                                 int* __restrict__ cnt, int E, int degBlocks,
                                                 const float* __restrict__ X,
                                                 const float* __restrict__ W,
                                                 __half* __restrict__ H, int Nrows) {
    __shared__ __align__(16) float xs[16][132];
    __shared__ __align__(16) float ws[16][128];
    int tid = threadIdx.x;
    if (blockIdx.x < degBlocks) {
        int base = blockIdx.x * 1024 + tid * 4;
        if (base + 3 < E) {
            int d0 = dst[base], d1 = dst[base + 1], d2 = dst[base + 2], d3 = dst[base + 3];
            atomicAdd(&cnt[d0], 1); atomicAdd(&cnt[d1], 1);
            atomicAdd(&cnt[d2], 1); atomicAdd(&cnt[d3], 1);
        } else {
            for (int e = base; e < E; ++e) atomicAdd(&cnt[dst[e]], 1);
        }
        return;
    }
    int tx = tid & 15;
    int ty = tid >> 4;
    int row0 = (blockIdx.x - degBlocks) * 128;
    float acc[8][8] = {};
    for (int k0 = 0; k0 < 128; k0 += 16) {
        {   // stage fp32 X tile transposed
            int r = tid >> 2;
            int j = (tid & 3) * 4;
            int gr = row0 + r;
            float4 v = (gr < Nrows) ? *(const float4*)&X[(size_t)gr * 128 + k0 + j]
                                    : make_float4(0.f, 0.f, 0.f, 0.f);
            xs[j + 0][r] = v.x; xs[j + 1][r] = v.y; xs[j + 2][r] = v.z; xs[j + 3][r] = v.w;
            int gr2 = gr + 64;
            float4 u = (gr2 < Nrows) ? *(const float4*)&X[(size_t)gr2 * 128 + k0 + j]
                                     : make_float4(0.f, 0.f, 0.f, 0.f);
            xs[j + 0][r + 64] = u.x; xs[j + 1][r + 64] = u.y;
            xs[j + 2][r + 64] = u.z; xs[j + 3][r + 64] = u.w;
        }
        {
            const float4* Wv = (const float4*)&W[(size_t)k0 * 128];
            float4* wsv = (float4*)&ws[0][0];
            wsv[tid] = Wv[tid];
            wsv[tid + 256] = Wv[tid + 256];
        }
        __syncthreads();
#pragma unroll
        for (int kk = 0; kk < 16; ++kk) {
            float4 xa = *(float4*)&xs[kk][ty * 4];
            float4 xb = *(float4*)&xs[kk][ty * 4 + 64];
            float4 wa = *(float4*)&ws[kk][tx * 4];
            float4 wb = *(float4*)&ws[kk][tx * 4 + 64];
            float xr[8] = {xa.x, xa.y, xa.z, xa.w, xb.x, xb.y, xb.z, xb.w};
            float wr[8] = {wa.x, wa.y, wa.z, wa.w, wb.x, wb.y, wb.z, wb.w};
#pragma unroll
            for (int i = 0; i < 8; ++i)
#pragma unroll
                for (int j = 0; j < 8; ++j)
                    acc[i][j] += xr[i] * wr[j];
        }
        __syncthreads();
    }
    auto pk = [](float x, float y) { __half2 h = __floats2half2_rn(x, y); return *(unsigned int*)&h; };
#pragma unroll
    for (int i = 0; i < 8; ++i) {
        int gr = row0 + ((i < 4) ? (ty * 4 + i) : (64 + ty * 4 + i - 4));
        if (gr < Nrows) {
            uint2 q0 = make_uint2(pk(acc[i][0], acc[i][1]), pk(acc[i][2], acc[i][3]));
            uint2 q1 = make_uint2(pk(acc[i][4], acc[i][5]), pk(acc[i][6], acc[i][7]));
            *(uint2*)&H[(size_t)gr * 128 + tx * 4] = q0;
            *(uint2*)&H[(size_t)gr * 128 + 64 + tx * 4] = q1;
        }
    }
}

// ---------------- fp16-in GEMM: H[N,128] = half((Xh @ W) * dscale[row]) ----------------
__global__ __launch_bounds__(256) void gemm128hh(const __half* __restrict__ Xh,
                                                 const float* __restrict__ W,
                                                 const float* __restrict__ dscale,
                                                 __half* __restrict__ H, int Nrows) {
    __shared__ __align__(16) float xs[16][132];
    __shared__ __align__(16) float ws[16][128];
    int tid = threadIdx.x;
    int tx = tid & 15;
    int ty = tid >> 4;
    int row0 = blockIdx.x * 128;
    float acc[8][8] = {};
    for (int k0 = 0; k0 < 128; k0 += 16) {
        {   // stage fp16 X tile transposed: 128 rows x 16 k, 8 halfs (uint4) per thread
            int r = tid >> 1;             // 0..127
            int jj = (tid & 1) * 8;       // 0 or 8
            int gr = row0 + r;
            if (gr < Nrows) {
                uint4 rw = *(const uint4*)&Xh[(size_t)gr * 128 + k0 + jj];
                const __half2* hp = (const __half2*)&rw;
#pragma unroll
                for (int m = 0; m < 4; ++m) {
                    float2 f = __half22float2(hp[m]);
                    xs[jj + 2 * m][r] = f.x;
                    xs[jj + 2 * m + 1][r] = f.y;
                }
            } else {
#pragma unroll
                for (int m = 0; m < 8; ++m) xs[jj + m][r] = 0.f;
            }
        }
        {
            const float4* Wv = (const float4*)&W[(size_t)k0 * 128];
            float4* wsv = (float4*)&ws[0][0];
            wsv[tid] = Wv[tid];
            wsv[tid + 256] = Wv[tid + 256];
        }
        __syncthreads();
#pragma unroll
        for (int kk = 0; kk < 16; ++kk) {
            float4 xa = *(float4*)&xs[kk][ty * 4];
            float4 xb = *(float4*)&xs[kk][ty * 4 + 64];
            float4 wa = *(float4*)&ws[kk][tx * 4];
            float4 wb = *(float4*)&ws[kk][tx * 4 + 64];
            float xr[8] = {xa.x, xa.y, xa.z, xa.w, xb.x, xb.y, xb.z, xb.w};
            float wr[8] = {wa.x, wa.y, wa.z, wa.w, wb.x, wb.y, wb.z, wb.w};
#pragma unroll
            for (int i = 0; i < 8; ++i)
#pragma unroll
                for (int j = 0; j < 8; ++j)
                    acc[i][j] += xr[i] * wr[j];
        }
        __syncthreads();
    }
    auto pk = [](float x, float y) { __half2 h = __floats2half2_rn(x, y); return *(unsigned int*)&h; };
#pragma unroll
    for (int i = 0; i < 8; ++i) {
        int gr = row0 + ((i < 4) ? (ty * 4 + i) : (64 + ty * 4 + i - 4));
        if (gr < Nrows) {
            float s = dscale[gr];
            uint2 q0 = make_uint2(pk(acc[i][0] * s, acc[i][1] * s), pk(acc[i][2] * s, acc[i][3] * s));
            uint2 q1 = make_uint2(pk(acc[i][4] * s, acc[i][5] * s), pk(acc[i][6] * s, acc[i][7] * s));
            *(uint2*)&H[(size_t)gr * 128 + tx * 4] = q0;
            *(uint2*)&H[(size_t)gr * 128 + 64 + tx * 4] = q1;
        }
    }
}

// ---------------- CSR aggregation over fp16 H -> fp16 out ----------------
// gdinv=1: H unscaled, gather dinv[s] per edge (layer 1).  gdinv=0: H pre-scaled.
// out = relu?(dinv[n]*sum + b), stored fp16.  256 threads = 16 nodes x 16 lanes,
// 8 halfs (uint4) per lane.  Unroll-4 -> 4 gathers in flight.  fp32 accumulation.
__global__ __launch_bounds__(256) void agg_h(const __half* __restrict__ H,
                                             const float* __restrict__ dinv,
                                             const int* __restrict__ rowptr,
                                             const int* __restrict__ col,
                                             const float* __restrict__ bias,
                                             __half* __restrict__ out,
                                             int n, int relu, int gdinv) {
    int node = blockIdx.x * 16 + (threadIdx.x >> 4);
    int t = (threadIdx.x & 15) * 8;       // dim offset (halfs)
    if (node >= n) return;
    int beg = rowptr[node], end = rowptr[node + 1];
    float a[8] = {};
    int k = beg;
    for (; k + 4 <= end; k += 4) {
        int s0 = col[k], s1 = col[k + 1], s2 = col[k + 2], s3 = col[k + 3];
        float w0 = 1.f, w1 = 1.f, w2 = 1.f, w3 = 1.f;
        if (gdinv) { w0 = dinv[s0]; w1 = dinv[s1]; w2 = dinv[s2]; w3 = dinv[s3]; }
        uint4 r0 = *(const uint4*)&H[(size_t)s0 * 128 + t];
        uint4 r1 = *(const uint4*)&H[(size_t)s1 * 128 + t];
        uint4 r2 = *(const uint4*)&H[(size_t)s2 * 128 + t];
        uint4 r3 = *(const uint4*)&H[(size_t)s3 * 128 + t];
        const __half2* h0 = (const __half2*)&r0;
        const __half2* h1 = (const __half2*)&r1;
        const __half2* h2 = (const __half2*)&r2;
        const __half2* h3 = (const __half2*)&r3;
#pragma unroll
        for (int j = 0; j < 4; ++j) {
            float2 f0 = __half22float2(h0[j]);
            float2 f1 = __half22float2(h1[j]);
            float2 f2 = __half22float2(h2[j]);
            float2 f3 = __half22float2(h3[j]);
            a[2 * j]     += f0.x * w0 + f1.x * w1 + f2.x * w2 + f3.x * w3;
            a[2 * j + 1] += f0.y * w0 + f1.y * w1 + f2.y * w2 + f3.y * w3;
        }
    }
    for (; k < end; ++k) {
        int s0 = col[k];
        float w0 = gdinv ? dinv[s0] : 1.f;
        uint4 r0 = *(const uint4*)&H[(size_t)s0 * 128 + t];
        const __half2* h0 = (const __half2*)&r0;
#pragma unroll
        for (int j = 0; j < 4; ++j) {
            float2 f0 = __half22float2(h0[j]);
            a[2 * j] += f0.x * w0;
            a[2 * j + 1] += f0.y * w0;
        }
    }
    float dn = dinv[node];
    float4 b0 = *(const float4*)&bias[t];
    float4 b1 = *(const float4*)&bias[t + 4];
    float r0 = a[0] * dn + b0.x, r1 = a[1] * dn + b0.y;
    float r2 = a[2] * dn + b0.z, r3 = a[3] * dn + b0.w;
    float r4 = a[4] * dn + b1.x, r5 = a[5] * dn + b1.y;
    float r6 = a[6] * dn + b1.z, r7 = a[7] * dn + b1.w;
    if (relu) {
        r0 = fmaxf(r0, 0.f); r1 = fmaxf(r1, 0.f); r2 = fmaxf(r2, 0.f); r3 = fmaxf(r3, 0.f);
        r4 = fmaxf(r4, 0.f); r5 = fmaxf(r5, 0.f); r6 = fmaxf(r6, 0.f); r7 = fmaxf(r7, 0.f);
    }
    auto pk = [](float x, float y) { __half2 h = __floats2half2_rn(x, y); return *(unsigned int*)&h; };
    uint4 o = make_uint4(pk(r0, r1), pk(r2, r3), pk(r4, r5), pk(r6, r7));
    *(uint4*)&out[(size_t)node * 128 + t] = o;
}

// ---------------- edge decoder over fp16 X: out[e] = dot(X[u], X[v]) ----------------
// 16 lanes per edge, 8 halfs (uint4) per lane; fp32 accumulate; 16-lane shuffle reduce.
__global__ __launch_bounds__(256) void decoder_h(const __half* __restrict__ X,
                                                 const int* __restrict__ eli,
                                                 float* __restrict__ out, int EL) {
    int e = blockIdx.x * 16 + (threadIdx.x >> 4);
    int lane = threadIdx.x & 15;
    if (e >= EL) return;
    int u = eli[e], v = eli[EL + e];
    uint4 ra = *(const uint4*)&X[(size_t)u * 128 + lane * 8];
    uint4 rb = *(const uint4*)&X[(size_t)v * 128 + lane * 8];
    const __half2* ha = (const __half2*)&ra;
    const __half2* hb = (const __half2*)&rb;
    float d = 0.f;
#pragma unroll
    for (int j = 0; j < 4; ++j) {
        float2 fa = __half22float2(ha[j]);
        float2 fb = __half22float2(hb[j]);
        d += fa.x * fb.x + fa.y * fb.y;
    }
#pragma unroll
    for (int off = 8; off > 0; off >>= 1) d += __shfl_xor(d, off);
    if (lane == 0) out[e] = d;
}

extern "C" void kernel_launch(void* const* d_in, const int* in_sizes, int n_in,
                              void* d_out, int out_size, void* d_ws, size_t ws_size,
                              hipStream_t stream) {
    const float* x0 = (const float*)d_in[0];
    const float* W1 = (const float*)d_in[1];
    const float* b1 = (const float*)d_in[2];
    const float* W2 = (const float*)d_in[3];
    const float* b2 = (const float*)d_in[4];
    const float* W3 = (const float*)d_in[5];
    const float* b3 = (const float*)d_in[6];
    const int* ei   = (const int*)d_in[7];
    const int* eli  = (const int*)d_in[8];
    float* out = (float*)d_out;

    const int D = 128;
    const int N  = in_sizes[0] / D;
    const int E  = in_sizes[7] / 2;
    const int EL = in_sizes[8] / 2;

    const int* src = ei;        // edge_index[0]
    const int* dst = ei + E;    // edge_index[1]

    // -------- workspace carve-up (256B aligned) --------
    char* ws = (char*)d_ws;
    size_t off = 0;
    auto alloc = [&](size_t bytes) -> void* {
        off = (off + 255) & ~(size_t)255;
        void* p = ws + off;
        off += bytes;
        return p;
    };
    int*    cnt    = (int*)alloc((size_t)N * sizeof(int));
    int*    tmp    = (int*)alloc((size_t)N * sizeof(int));
    int*    bsum   = (int*)alloc(256 * sizeof(int));
    int*    rowptr = (int*)alloc((size_t)(N + 1) * sizeof(int));
    float*  dinv   = (float*)alloc((size_t)N * sizeof(float));
    int*    col    = (int*)alloc((size_t)(E + N) * sizeof(int));
    __half* hbuf   = (__half*)alloc((size_t)N * D * sizeof(__half));  // gemm out
    __half* xbuf   = (__half*)alloc((size_t)N * D * sizeof(__half));  // agg out
    (void)ws_size;

    // zero the degree counters
    hipMemsetAsync(cnt, 0, (size_t)N * sizeof(int), stream);

    int nbN = (N + 255) / 256;
    int nbE4 = (E + 1023) / 1024;
    int gemmGrid = (N + 127) / 128;
    int aggGrid  = (N + 15) / 16;

    // ---- MEGA: degree histogram + unscaled layer-1 GEMM in one dispatch ----
    deg_gemm1<<<nbE4 + gemmGrid, 256, 0, stream>>>(dst, cnt, E, nbE4, x0, W1, hbuf, N);

    // ---- scan chain -> rowptr/dinv/self-loops ----
    scan1<<<nbN, 256, 0, stream>>>(cnt, tmp, bsum, N);
    scan2<<<1, 256, 0, stream>>>(bsum, nbN);
    scan3<<<nbN, 256, 0, stream>>>(tmp, bsum, cnt, rowptr, dinv, col, N);
    edgefill4<<<nbE4, 256, 0, stream>>>(src, dst, rowptr, cnt, col, E);

    // ---- layer 1: agg gathers dinv[s] per edge (H1 unscaled) ----
    agg_h<<<aggGrid, 256, 0, stream>>>(hbuf, dinv, rowptr, col, b1, xbuf, N, 1, 1);
    // ---- layer 2 ----
    gemm128hh<<<gemmGrid, 256, 0, stream>>>(xbuf, W2, dinv, hbuf, N);
    agg_h<<<aggGrid, 256, 0, stream>>>(hbuf, dinv, rowptr, col, b2, xbuf, N, 1, 0);
    // ---- layer 3 ----
    gemm128hh<<<gemmGrid, 256, 0, stream>>>(xbuf, W3, dinv, hbuf, N);
    agg_h<<<aggGrid, 256, 0, stream>>>(hbuf, dinv, rowptr, col, b3, xbuf, N, 0, 0);

    // ---- decoder ----
    decoder_h<<<(EL + 15) / 16, 256, 0, stream>>>(xbuf, eli, out, EL);
}